// Round 3
// baseline (75693.469 us; speedup 1.0000x reference)
//
#include <hip/hip_runtime.h>
#include <stdint.h>

#define DZ 128
#define DX 256
#define TT 100000
#define TC 64

// ---------------------------------------------------------------------------
// Scan kernel: 1 block, 256 threads (4 waves, 1/SIMD). Thread t: jg = t&3
// (32-col slice), rs = t>>2 (row pair r0 = rs*2). W1/W2 slices live in
// registers (f32, ~128 VGPR; launch_bounds(256,1) allows 512). x broadcast
// through LDS with bank-rotated chunk order ((i+jg)&7 — the 4 jg groups'
// addresses are all ≡ same banks mod 128B otherwise → 4-way conflict).
// Weights are loaded in the SAME rotated order so register indices stay
// compile-time constants (rule #20). 4-lane shfl_xor reduce (DPP quad_perm).
// Recurrence entirely in f32.
// ---------------------------------------------------------------------------
__global__ __launch_bounds__(256, 1)
void scan_kernel(const float* __restrict__ AW1, const float* __restrict__ AW2,
                 const float* __restrict__ h1g, const float* __restrict__ h2g,
                 const float* __restrict__ Qg,  const float* __restrict__ z0g,
                 const float* __restrict__ a0g, const float* __restrict__ epsg,
                 float* __restrict__ Zout) {
    __shared__ float xbuf[DZ];
    __shared__ float ubuf[DZ];

    const int tid = threadIdx.x;
    const int jg  = tid & 3;
    const int rs  = tid >> 2;
    const int r0  = rs * 2;
    const int jbase = jg * 32;

    // ---- weight slices into registers, rotated chunk order, diag zeroed ----
    float w1[2][32], w2[2][32];
    #pragma unroll
    for (int k = 0; k < 2; ++k) {
        const int r = r0 + k;
        #pragma unroll
        for (int i = 0; i < 8; ++i) {
            const int cb = jbase + (((i + jg) & 7) << 2);
            #pragma unroll
            for (int l = 0; l < 4; ++l) {
                const int col = cb + l;
                const float v1 = AW1[r * DZ + col];
                const float v2 = AW2[r * DZ + col];
                const bool diag = (col == r);
                w1[k][i * 4 + l] = diag ? 0.f : v1;
                w2[k][i * 4 + l] = diag ? 0.f : v2;
            }
        }
    }
    float a1v[2], a2v[2], h1v[2], h2v[2], Qv[2], z[2], at[2];
    #pragma unroll
    for (int k = 0; k < 2; ++k) {
        const int r = r0 + k;
        a1v[k] = AW1[r * DZ + r];
        a2v[k] = AW2[r * DZ + r];
        h1v[k] = h1g[r];
        h2v[k] = h2g[r];
        Qv[k]  = Qg[r];
        z[k]   = z0g[r];
        at[k]  = a0g[r];
    }

    // bootstrap xbuf = relu(z0)
    if (jg == 0) {
        *(float2*)(xbuf + r0) = make_float2(fmaxf(z[0], 0.f), fmaxf(z[1], 0.f));
    }
    __syncthreads();

    // eps prefetch: one float2 (2 rows) per step, 8-step blocks, 1 block ahead
    const float2* epw = (const float2*)epsg;   // index: t*64 + rs
    float2 eps_cur[8], eps_nxt[8];
    #pragma unroll
    for (int s = 0; s < 8; ++s) eps_cur[s] = epw[(size_t)s * 64 + rs];
    #pragma unroll
    for (int s = 0; s < 8; ++s) eps_nxt[s] = epw[(size_t)(8 + s) * 64 + rs];

    float zs0[8], zs1[8];

    for (int tb = 0; tb < TT; tb += 8) {
        #pragma unroll
        for (int s = 0; s < 8; ++s) {
            // ---------------- MV1: mv = W1 @ relu(z_t) ---------------------
            float xj[32];
            #pragma unroll
            for (int i = 0; i < 8; ++i) {
                const float4 t4 =
                    *(const float4*)(xbuf + jbase + (((i + jg) & 7) << 2));
                xj[i*4+0] = t4.x; xj[i*4+1] = t4.y;
                xj[i*4+2] = t4.z; xj[i*4+3] = t4.w;
            }
            float m0a = 0.f, m0b = 0.f, m1a = 0.f, m1b = 0.f;
            #pragma unroll
            for (int j = 0; j < 32; j += 2) {
                m0a = fmaf(w1[0][j],   xj[j],   m0a);
                m0b = fmaf(w1[0][j+1], xj[j+1], m0b);
                m1a = fmaf(w1[1][j],   xj[j],   m1a);
                m1b = fmaf(w1[1][j+1], xj[j+1], m1b);
            }
            // bt = sigmoid(z)*(h1-z) (overlaps MV1 on trans pipe)
            const float e0 = expf(-z[0]);
            const float e1 = expf(-z[1]);
            const float bt0 = (h1v[0] - z[0]) / (1.f + e0);
            const float bt1 = (h1v[1] - z[1]) / (1.f + e1);

            float mv0 = m0a + m0b, mv1 = m1a + m1b;
            mv0 += __shfl_xor(mv0, 1, 64); mv0 += __shfl_xor(mv0, 2, 64);
            mv1 += __shfl_xor(mv1, 1, 64); mv1 += __shfl_xor(mv1, 2, 64);

            at[0] = fmaf(a1v[0], at[0], mv0);
            at[1] = fmaf(a1v[1], at[1], mv1);
            const float u0 = at[0] * bt0;
            const float u1 = at[1] * bt1;
            if (jg == 0) *(float2*)(ubuf + r0) = make_float2(u0, u1);
            __syncthreads();

            // ---------------- MV2: n = W2 @ u ------------------------------
            #pragma unroll
            for (int i = 0; i < 8; ++i) {
                const float4 t4 =
                    *(const float4*)(ubuf + jbase + (((i + jg) & 7) << 2));
                xj[i*4+0] = t4.x; xj[i*4+1] = t4.y;
                xj[i*4+2] = t4.z; xj[i*4+3] = t4.w;
            }
            float n0a = 0.f, n0b = 0.f, n1a = 0.f, n1b = 0.f;
            #pragma unroll
            for (int j = 0; j < 32; j += 2) {
                n0a = fmaf(w2[0][j],   xj[j],   n0a);
                n0b = fmaf(w2[0][j+1], xj[j+1], n0b);
                n1a = fmaf(w2[1][j],   xj[j],   n1a);
                n1b = fmaf(w2[1][j+1], xj[j+1], n1b);
            }
            float n0 = n0a + n0b, n1 = n1a + n1b;
            n0 += __shfl_xor(n0, 1, 64); n0 += __shfl_xor(n0, 2, 64);
            n1 += __shfl_xor(n1, 1, 64); n1 += __shfl_xor(n1, 2, 64);

            z[0] = fmaf(a2v[0], z[0], n0 + fmaf(Qv[0], eps_cur[s].x, h2v[0]));
            z[1] = fmaf(a2v[1], z[1], n1 + fmaf(Qv[1], eps_cur[s].y, h2v[1]));

            zs0[s] = z[0];
            zs1[s] = z[1];

            // publish relu(z_{t+1}) for next step
            if (jg == 0)
                *(float2*)(xbuf + r0) =
                    make_float2(fmaxf(z[0], 0.f), fmaxf(z[1], 0.f));
            __syncthreads();
        }

        if (jg == 0) {
            float* d0 = Zout + (size_t)r0 * TT + tb;
            float* d1 = Zout + (size_t)(r0 + 1) * TT + tb;
            *(float4*)(d0)     = make_float4(zs0[0], zs0[1], zs0[2], zs0[3]);
            *(float4*)(d0 + 4) = make_float4(zs0[4], zs0[5], zs0[6], zs0[7]);
            *(float4*)(d1)     = make_float4(zs1[0], zs1[1], zs1[2], zs1[3]);
            *(float4*)(d1 + 4) = make_float4(zs1[4], zs1[5], zs1[6], zs1[7]);
        }

        // rotate eps and prefetch block tb+16
        #pragma unroll
        for (int s = 0; s < 8; ++s) eps_cur[s] = eps_nxt[s];
        int tnx = tb + 16;
        if (tnx >= TT) tnx = 0;   // harmless dummy prefetch on last blocks
        #pragma unroll
        for (int s = 0; s < 8; ++s)
            eps_nxt[s] = epw[(size_t)(tnx + s) * 64 + rs];
    }
}

// ---------------------------------------------------------------------------
// Emission kernel: X = B @ Z + R[:,None] * eta.T  (all f32)
// grid over 64-wide t tiles; Z tile in LDS (32 KB); B L2-resident.
// thread: 4 X-rows x 16 t.
// ---------------------------------------------------------------------------
__global__ __launch_bounds__(256, 2)
void emit_kernel(const float* __restrict__ Bm, const float* __restrict__ Rg,
                 const float* __restrict__ etag, const float* __restrict__ Zg,
                 float* __restrict__ Xout) {
    __shared__ float zt[DZ][TC];

    const int tid = threadIdx.x;
    const int t0  = blockIdx.x * TC;

    // ---- cooperative Z tile load (row zk, 32 cols per thread) ----
    {
        const int zk    = tid >> 1;
        const int ztoff = (tid & 1) * 32;
        const float* src = Zg + (size_t)zk * TT + t0 + ztoff;
        #pragma unroll
        for (int c = 0; c < 8; ++c) {
            const int tt = t0 + ztoff + c * 4;      // TT % 4 == 0: no straddle
            float4 v = make_float4(0.f, 0.f, 0.f, 0.f);
            if (tt < TT) v = *(const float4*)(src + c * 4);
            *(float4*)&zt[zk][ztoff + c * 4] = v;
        }
    }
    __syncthreads();

    const int rs = tid >> 2;          // 64 row-sets of 4 X-rows
    const int r0 = rs * 4;
    const int ts = tid & 3;           // 4 t-sets of 16
    const int tbase = t0 + ts * 16;

    float acc[4][16];
    #pragma unroll
    for (int i = 0; i < 4; ++i)
        #pragma unroll
        for (int t = 0; t < 16; ++t) acc[i][t] = 0.f;

    for (int kc = 0; kc < 16; ++kc) {            // K chunks of 8
        float bb[4][8];
        #pragma unroll
        for (int i = 0; i < 4; ++i) {
            const float* bp = Bm + (size_t)(r0 + i) * DZ + kc * 8;
            const float4 p0 = *(const float4*)(bp);
            const float4 p1 = *(const float4*)(bp + 4);
            bb[i][0] = p0.x; bb[i][1] = p0.y; bb[i][2] = p0.z; bb[i][3] = p0.w;
            bb[i][4] = p1.x; bb[i][5] = p1.y; bb[i][6] = p1.z; bb[i][7] = p1.w;
        }
        #pragma unroll
        for (int k = 0; k < 8; ++k) {
            float zv[16];
            #pragma unroll
            for (int c = 0; c < 4; ++c) {
                const float4 z4 = *(const float4*)&zt[kc * 8 + k][ts * 16 + c * 4];
                zv[c*4+0] = z4.x; zv[c*4+1] = z4.y;
                zv[c*4+2] = z4.z; zv[c*4+3] = z4.w;
            }
            #pragma unroll
            for (int i = 0; i < 4; ++i) {
                const float bv = bb[i][k];
                #pragma unroll
                for (int t = 0; t < 16; ++t)
                    acc[i][t] = fmaf(bv, zv[t], acc[i][t]);
            }
        }
    }

    // ---- epilogue: + R*eta, store (TT % 16 == 0: per-thread columns fully
    //      valid or fully out of range) ----
    if (tbase < TT) {
        float Rv[4];
        #pragma unroll
        for (int i = 0; i < 4; ++i) Rv[i] = Rg[r0 + i];

        float ev[16][4];
        #pragma unroll
        for (int t = 0; t < 16; ++t) {
            const float4 e = *(const float4*)(etag + (size_t)(tbase + t) * DX + r0);
            ev[t][0] = e.x; ev[t][1] = e.y; ev[t][2] = e.z; ev[t][3] = e.w;
        }
        #pragma unroll
        for (int i = 0; i < 4; ++i) {
            float o[16];
            #pragma unroll
            for (int t = 0; t < 16; ++t)
                o[t] = fmaf(Rv[i], ev[t][i], acc[i][t]);
            float* dst = Xout + (size_t)(r0 + i) * TT + tbase;
            *(float4*)(dst)      = make_float4(o[0],  o[1],  o[2],  o[3]);
            *(float4*)(dst + 4)  = make_float4(o[4],  o[5],  o[6],  o[7]);
            *(float4*)(dst + 8)  = make_float4(o[8],  o[9],  o[10], o[11]);
            *(float4*)(dst + 12) = make_float4(o[12], o[13], o[14], o[15]);
        }
    }
}

// ---------------------------------------------------------------------------
extern "C" void kernel_launch(void* const* d_in, const int* in_sizes, int n_in,
                              void* d_out, int out_size, void* d_ws, size_t ws_size,
                              hipStream_t stream) {
    const float* AW1 = (const float*)d_in[0];
    const float* AW2 = (const float*)d_in[1];
    const float* h1  = (const float*)d_in[2];
    const float* h2  = (const float*)d_in[3];
    const float* Bm  = (const float*)d_in[4];
    const float* Q   = (const float*)d_in[5];
    const float* R   = (const float*)d_in[6];
    const float* z0  = (const float*)d_in[7];
    const float* a0  = (const float*)d_in[8];
    const float* eps = (const float*)d_in[9];
    const float* eta = (const float*)d_in[10];

    float* Xout = (float*)d_out;
    float* Zout = Xout + (size_t)DX * TT;

    hipLaunchKernelGGL(scan_kernel, dim3(1), dim3(256), 0, stream,
                       AW1, AW2, h1, h2, Q, z0, a0, eps, Zout);

    hipLaunchKernelGGL(emit_kernel, dim3((TT + TC - 1) / TC), dim3(256), 0, stream,
                       Bm, R, eta, Zout, Xout);
}